// Round 2
// baseline (1742.907 us; speedup 1.0000x reference)
//
#include <hip/hip_runtime.h>
#include <hip/hip_bf16.h>
#include <stdint.h>

// ---------------- problem constants ----------------
constexpr int NN = 100000;     // nodes
constexpr int NE = 1600000;    // edges
constexpr int NG = 64;         // graphs
constexpr int NB_SCAN = 98;    // ceil(100000/1024)

// Chunk-major node-feature layout: [chunk][node][16 feats] bf16, 32B rows.
// x-buffers (gather sources) carry a zero sentinel row at node==NN.
constexpr int ST0 = NN + 1;                 // node slots per chunk, x-buffers (A0)
constexpr int ST1 = NN;                     // node slots per chunk, y-buffers (A1)
constexpr size_t CB0 = (size_t)ST0 * 32;    // 3,200,032 B per chunk
constexpr size_t CB1 = (size_t)ST1 * 32;    // 3,200,000 B per chunk

// prep kernel grid sections (convx | indeg+slot | convw(W0..W2) | nstart)
constexpr int PREP_CONVX_BLK = 12500;   // NN*32/256
constexpr int PREP_INDEG_BLK = 1563;    // ceil(NE/4/256)
constexpr int PREP_CONVW_BLK = 384;     // (24576+36864+36864)/256
constexpr int PREP_GB_BLK    = 391;     // ceil(NN/256)
constexpr int PREP_GRID = PREP_CONVX_BLK + PREP_INDEG_BLK + PREP_CONVW_BLK + PREP_GB_BLK;

// E-GEMM geometry
constexpr int EG_BLOCKS = 391;            // ceil(NN/256), 256 src rows per block
constexpr int HROW = 50048;               // hist row length in u32 (EG_BLOCKS*256/2)

typedef __bf16 bf16x8 __attribute__((ext_vector_type(8)));
typedef float  f32x16 __attribute__((ext_vector_type(16)));
typedef float  f32x4  __attribute__((ext_vector_type(4)));
typedef unsigned int u32x2 __attribute__((ext_vector_type(2)));

union U16x4 { uint4 u; bf16x8 b; };

// bf16(packed in uint halves) <-> f32 helpers
__device__ __forceinline__ float bl(unsigned int u) { return __uint_as_float(u << 16); }
__device__ __forceinline__ float bh(unsigned int u) { return __uint_as_float(u & 0xffff0000u); }
__device__ __forceinline__ float b16f(unsigned short u) { return __uint_as_float(((unsigned int)u) << 16); }
__device__ __forceinline__ unsigned int fb(float f) {  // f32 -> bf16 bits, RTNE
    unsigned int u = __float_as_uint(f);
    return (u + 0x7fffu + ((u >> 16) & 1u)) >> 16;
}
// packed bf16 relu: v_pk_max_f16 on raw bits decides on sign/zero only — exact for bf16.
__device__ __forceinline__ unsigned int prelu(unsigned int u) {
    unsigned int r;
    asm("v_pk_max_f16 %0, %1, %2" : "=v"(r) : "v"(u), "v"(0u));
    return r;
}
// two u16 counts -> packed bf16 pair (exact for counts <= 256)
__device__ __forceinline__ unsigned int cnt2bf(unsigned int h) {
    float f0 = (float)(h & 0xffffu);
    float f1 = (float)(h >> 16);
    return (__float_as_uint(f0) >> 16) | (__float_as_uint(f1) & 0xffff0000u);
}

// ---------------- fused preprocessing: convx | indeg+slot | convw | nstart ----------------
__global__ __launch_bounds__(256) void k_prep(const float* __restrict__ x,
                                              const int* __restrict__ ei,
                                              const int* __restrict__ bat,
                                              const float* __restrict__ W0, const float* __restrict__ W1,
                                              const float* __restrict__ W2,
                                              unsigned short* __restrict__ A_,
                                              int* __restrict__ indeg, int* __restrict__ slot,
                                              unsigned short* __restrict__ T0, unsigned short* __restrict__ T1,
                                              unsigned short* __restrict__ T2,
                                              int* __restrict__ nstart) {
    const int b = blockIdx.x;
    if (b < PREP_CONVX_BLK) {
        int id = b * 256 + threadIdx.x;
        if (id < 96) {   // zero sentinel rows: 12 chunks x 32B
            int cc = id >> 3, u = id & 7;
            ((unsigned int*)(A_ + ((size_t)cc * ST0 + NN) * 16))[u] = 0u;
        }
        // id -> (chunk cc, node, quarter q); x0 has 8 chunks (128 feats)
        int cc = id / 400000;
        int r  = id - cc * 400000;
        int node = r >> 2, q = r & 3;
        float4 v = ((const float4*)x)[node * 32 + cc * 4 + q];
        uint2 a;
        a.x = fb(v.x) | (fb(v.y) << 16);
        a.y = fb(v.z) | (fb(v.w) << 16);
        *(uint2*)(A_ + ((size_t)cc * ST0 + node) * 16 + q * 4) = a;
    } else if (b < PREP_CONVX_BLK + PREP_INDEG_BLK) {
        int e4 = ((b - PREP_CONVX_BLK) * 256 + threadIdx.x) * 4;
        if (e4 < NE) {
            int4 d = *(const int4*)(ei + NE + e4);
            int4 sl;
            sl.x = atomicAdd(&indeg[d.x], 1);
            sl.y = atomicAdd(&indeg[d.y], 1);
            sl.z = atomicAdd(&indeg[d.z], 1);
            sl.w = atomicAdd(&indeg[d.w], 1);
            *(int4*)(slot + e4) = sl;
        }
    } else if (b < PREP_CONVX_BLK + PREP_INDEG_BLK + PREP_CONVW_BLK) {
        int id = (b - PREP_CONVX_BLK - PREP_INDEG_BLK) * 256 + threadIdx.x;
        const float* W; unsigned short* T; int N, base;
        if      (id < 24576) { W = W0; T = T0; N = 192; base = 0;     }
        else if (id < 61440) { W = W1; T = T1; N = 192; base = 24576; }
        else                 { W = W2; T = T2; N = 192; base = 61440; }
        int lid = id - base;
        int ci = lid >> 3, j = lid & 7;
        int kc = ci / N, n = ci % N;
        T[lid] = (unsigned short)fb(W[(kc * 8 + j) * N + n]);
    } else {
        // nstart[g] = first node n with bat[n] >= g (batch sorted); empty graphs ok
        int n = (b - PREP_CONVX_BLK - PREP_INDEG_BLK - PREP_CONVW_BLK) * 256 + threadIdx.x;
        if (n < NN) {
            int b0 = bat[n];
            int bprev = (n == 0) ? -1 : bat[n - 1];
            for (int g = bprev + 1; g <= b0; g++) nstart[g] = n;
            if (n == NN - 1)
                for (int g = b0 + 1; g < NG; g++) nstart[g] = NN;
        }
    }
}

// ---------------- scan of indeg -> offs (+ degree histogram for counting sort) ----------------
__global__ __launch_bounds__(1024) void k_scan1(const int* __restrict__ indeg, int* __restrict__ offs,
                                                int* __restrict__ partials, int* __restrict__ dbin) {
    __shared__ int s[1024];
    int t = threadIdx.x;
    int gid = blockIdx.x * 1024 + t;
    int v = (gid < NN) ? indeg[gid] : 0;
    if (gid < NN) atomicAdd(&dbin[min(v, 255)], 1);
    s[t] = v;
    __syncthreads();
    for (int d = 1; d < 1024; d <<= 1) {
        int tv = (t >= d) ? s[t - d] : 0;
        __syncthreads();
        s[t] += tv;
        __syncthreads();
    }
    if (gid < NN) offs[gid + 1] = s[t];
    if (t == 1023) partials[blockIdx.x] = s[1023];
}

// dual scan: 98 block-partials AND 256 degree bins (exclusive)
__global__ __launch_bounds__(256) void k_scan2(int* __restrict__ offs, int* __restrict__ partials,
                                               const int* __restrict__ dbin, int* __restrict__ dboff) {
    __shared__ int s[128];
    __shared__ int db[256];
    int t = threadIdx.x;
    int v = 0;
    if (t < 128) { v = (t < NB_SCAN) ? partials[t] : 0; s[t] = v; }
    int dv = dbin[t];
    db[t] = dv;
    __syncthreads();
    for (int d = 1; d < 256; d <<= 1) {
        int tv = (t < 128 && t >= d && d < 128) ? s[t - d] : 0;
        int tb = (t >= d) ? db[t - d] : 0;
        __syncthreads();
        if (t < 128 && d < 128) s[t] += tv;
        db[t] += tb;
        __syncthreads();
    }
    if (t < NB_SCAN) partials[t] = s[t] - v;
    dboff[t] = db[t] - dv;            // exclusive bin offsets
    if (t == 0) offs[0] = 0;
}

// apply partials + counting-sort scatter (perm = nodes sorted by degree)
__global__ __launch_bounds__(1024) void k_scan3(int* __restrict__ offs, const int* __restrict__ partials,
                                                const int* __restrict__ indeg, int* __restrict__ dboff,
                                                int* __restrict__ perm) {
    int gid = blockIdx.x * 1024 + threadIdx.x;
    if (gid < NN) {
        offs[gid + 1] += partials[blockIdx.x];
        int b = min(indeg[gid], 255);
        int pos = atomicAdd(&dboff[b], 1);
        perm[pos] = gid;
    }
}

// pack {node, deg, offs} per degree-sorted slot (coalesced int4 for the agg kernels)
__global__ __launch_bounds__(256) void k_pgather(const int* __restrict__ perm, const int* __restrict__ indeg,
                                                 const int* __restrict__ offs, int4* __restrict__ parr) {
    int s = blockIdx.x * 256 + threadIdx.x;   // 391*256 = 100096 exactly
    if (s < NN) {
        int n = perm[s];
        parr[s] = (int4){n, indeg[n], offs[n], 0};
    } else {
        parr[s] = (int4){NN, 0, 0, 0};
    }
}

// ---------------- atomic-free CSR fill ----------------
__global__ __launch_bounds__(256) void k_fill(const int* __restrict__ ei, const int* __restrict__ offs,
                                              const int* __restrict__ slot, int* __restrict__ csr) {
    int e4 = (blockIdx.x * 256 + threadIdx.x) * 4;
    if (e4 >= NE) return;
    int4 sv = *(const int4*)(ei + e4);
    int4 dv = *(const int4*)(ei + NE + e4);
    int4 sl = *(const int4*)(slot + e4);
    csr[offs[dv.x] + sl.x] = sv.x;
    csr[offs[dv.y] + sl.y] = sv.y;
    csr[offs[dv.z] + sl.z] = sv.z;
    csr[offs[dv.w] + sl.w] = sv.w;
}

// ---------------- aggregation (layers 0..2), chunk-major, L2-resident ----------------
// One pass per 16-feature chunk (32B rows, 3.2MB working set < 4MB L2/XCD); half-chunk
// items pinned to XCDs via blockIdx%8. Wave = 16 nodes x 4 lanes (8B/lane).
// Nodes are processed in degree-sorted order (parr) so the 16 nodes of a wave have
// ~equal degree -> __any loop has ~no divergence waste. 16-deep edge batching per lane
// (16 outstanding gathers) restores memory-level parallelism; csr loads nt-hinted so
// the stream doesn't evict the L2-resident chunk.
template <int CH>   // chunks: 8 (128-wide) or 12 (192-wide)
__global__ __launch_bounds__(256, 8) void k_aggc(const unsigned short* __restrict__ Ain,
                                                 unsigned short* __restrict__ Yout,
                                                 const int4* __restrict__ parr,
                                                 const int* __restrict__ csr) {
    constexpr int IPX = CH / 4;            // half-chunk items per XCD (2 or 3)
    constexpr int NBH = 782;               // 64-node blocks per half (782*64 = 50048)
    const int x   = blockIdx.x & 7;        // presumed XCD (round-robin dispatch)
    const int jj  = blockIdx.x >> 3;
    const int il  = jj / NBH;              // item_local, sequential per XCD
    const int nbl = jj - il * NBH;
    const int item = x * IPX + il;         // 0..2*CH-1
    const int c = item >> 1, h = item & 1; // chunk, slot-half
    const int l = threadIdx.x & 63, wv = threadIdx.x >> 6;
    const int g = l >> 2, q = l & 3;       // node-sub 0..15, 8B piece 0..3
    const int slot = h * 50048 + nbl * 64 + wv * 16 + g;
    const int4 pd = parr[slot];            // {node, deg, offs}
    const int node = pd.x;
    const int deg = pd.y;
    const char* Ab = (const char*)Ain + (size_t)c * CB0;
    const unsigned qo = (unsigned)(q * 8);

    f32x4 acc;
    {
        uint2 p = *(const uint2*)(Ab + (unsigned)node * 32u + qo);
        const float ed = 1e-7f * (float)deg;
        acc = (f32x4){bl(p.x) + ed, bh(p.x) + ed, bl(p.y) + ed, bh(p.y) + ed};
    }

    const int* ec = csr + pd.z;
    for (int e = 0; __any(e < deg); e += 16) {
        int idx[16];
#pragma unroll
        for (int k = 0; k < 16; k++)
            idx[k] = __builtin_nontemporal_load(ec + e + k);
        uint2 p[16];
#pragma unroll
        for (int k = 0; k < 16; k++) {
            unsigned n = (e + k < deg) ? (unsigned)idx[k] : (unsigned)NN;
            p[k] = *(const uint2*)(Ab + n * 32u + qo);
        }
#pragma unroll
        for (int k = 0; k < 16; k++) {
            unsigned r = prelu(p[k].x);
            acc.x += bl(r); acc.y += bh(r);
            r = prelu(p[k].y);
            acc.z += bl(r); acc.w += bh(r);
        }
    }
    if (slot < NN) {
        u32x2 o;
        o.x = fb(acc.x) | (fb(acc.y) << 16);
        o.y = fb(acc.z) | (fb(acc.w) << 16);
        *(u32x2*)((char*)Yout + (size_t)c * CB1 + (unsigned)node * 32u + qo) = o;
    }
}

// ---------------- GEMM: h = y @ W + b (layers 0..2) ----------------
// A-operand read from chunk-major y (stride ST1): per ks, wave reads 1KB contiguous.
// Epilogue writes x chunk-major (stride ST0).
template <int K, int N>
__global__ __launch_bounds__(256) void k_gemm(const unsigned short* __restrict__ Yin,
                                              const unsigned short* __restrict__ WtC,
                                              const float* __restrict__ bias,
                                              unsigned short* __restrict__ Aout) {
    static_assert(K % 16 == 0 && N % 32 == 0, "");
    const int w = threadIdx.x >> 6, lane = threadIdx.x & 63;
    const int rt = blockIdx.x * 4 + w;
    if (rt >= (NN / 32)) return;
    const int hl = lane >> 5, lr = lane & 31;
    const int row0 = rt * 32;
    f32x16 acc[N / 32];
#pragma unroll
    for (int c = 0; c < N / 32; c++)
#pragma unroll
        for (int r = 0; r < 16; r++) acc[c][r] = 0.f;

    const unsigned short* ap = Yin + (size_t)(row0 + lr) * 16 + hl * 8;
    const uint4* b4 = (const uint4*)WtC;
#pragma unroll
    for (int ks = 0; ks < K / 16; ks++) {
        U16x4 a;
        a.u = *(const uint4*)(ap + (size_t)ks * (ST1 * 16));
#pragma unroll
        for (int c = 0; c < N / 32; c++) {
            U16x4 b;
            b.u = b4[(ks * 2 + hl) * N + c * 32 + lr];
            acc[c] = __builtin_amdgcn_mfma_f32_32x32x16_bf16(a.b, b.b, acc[c], 0, 0, 0);
        }
    }
#pragma unroll
    for (int c = 0; c < N / 32; c++) {
        const int col = c * 32 + lr;
        const float bc = bias[col];
        const int cc = col >> 4, co = col & 15;
#pragma unroll
        for (int r = 0; r < 16; r++) {
            const int row = row0 + (r & 3) + 8 * (r >> 2) + 4 * hl;
            Aout[((size_t)cc * ST0 + row) * 16 + co] = (unsigned short)fb(acc[c][r] + bc);
        }
    }
}

// ---------------- layer-3 replacement: E-matrix path ----------------
__global__ __launch_bounds__(256) void k_hist(const int* __restrict__ csr, const int* __restrict__ offs,
                                              const int* __restrict__ nstart,
                                              unsigned int* __restrict__ hist) {
    const int g = blockIdx.x >> 2, q = blockIdx.x & 3;
    const int s0 = offs[nstart[g]];
    const int s1 = (g == NG - 1) ? NE : offs[nstart[g + 1]];
    const int len = s1 - s0;
    const int qs = s0 + (int)(((long long)len * q) >> 2);
    const int qe = s0 + (int)(((long long)len * (q + 1)) >> 2);
    unsigned int* hrow = hist + (size_t)g * HROW;
    for (int p = qs + threadIdx.x; p < qe; p += 256) {
        int src = csr[p];
        atomicAdd(&hrow[src >> 1], 1u << (16 * (src & 1)));
    }
}

// msg-partials: P[g][f] += count(j->g) * relu(x3[j][f]) over block's 256-row K slice.
__global__ __launch_bounds__(384) void k_egemm(const unsigned short* __restrict__ A0,
                                               const unsigned int* __restrict__ hist,
                                               float* __restrict__ partials) {
    const int wv = threadIdx.x >> 6, lane = threadIdx.x & 63;
    const int b = blockIdx.x;
    const int j0 = b * 256;
    const int hl = lane >> 5, lr = lane & 31;
    const int feat = wv * 32 + lr;
    const size_t fof = (size_t)(feat >> 4) * (ST0 * 16) + (feat & 15);
    f32x16 acc[2];
#pragma unroll
    for (int m = 0; m < 2; m++)
#pragma unroll
        for (int r = 0; r < 16; r++) acc[m][r] = 0.f;

    for (int kk = 0; kk < 16; kk++) {
        // A-operand: counts for g = m*32+lr, j = j0+kk*16+hl*8 .. +8
        const int jh = (j0 >> 1) + kk * 8 + hl * 4;
        U16x4 af[2];
#pragma unroll
        for (int m = 0; m < 2; m++) {
            uint4 h = *(const uint4*)(hist + (size_t)(m * 32 + lr) * HROW + jh);
            af[m].u = (uint4){cnt2bf(h.x), cnt2bf(h.y), cnt2bf(h.z), cnt2bf(h.w)};
        }
        // B-operand: relu(x3[j][feat]) for the same 8 j (chunk-major x3)
        U16x4 bf_;
#pragma unroll
        for (int tp = 0; tp < 4; tp++) {
            int je = j0 + kk * 16 + hl * 8 + tp * 2;
            int ja = min(je, NN), jb = min(je + 1, NN);   // sentinel zero row
            unsigned int u0 = A0[fof + (size_t)ja * 16];
            unsigned int u1 = A0[fof + (size_t)jb * 16];
            ((unsigned int*)&bf_.u)[tp] = prelu(u0 | (u1 << 16));
        }
#pragma unroll
        for (int m = 0; m < 2; m++)
            acc[m] = __builtin_amdgcn_mfma_f32_32x32x16_bf16(af[m].b, bf_.b, acc[m], 0, 0, 0);
    }
    float* pb = partials + (size_t)b * 12288;
#pragma unroll
    for (int m = 0; m < 2; m++)
#pragma unroll
        for (int r = 0; r < 16; r++) {
            const int g = m * 32 + (r & 3) + 8 * (r >> 2) + 4 * hl;
            pb[g * 192 + feat] = acc[m][r];
        }
}

// reduce f32 partials -> msg f32 [64][192]
__global__ __launch_bounds__(256) void k_reduce(const float* __restrict__ partials,
                                                float* __restrict__ msg) {
    int gf = blockIdx.x * 256 + threadIdx.x;     // 12288 total
    if (gf >= 12288) return;
    float s = 0.f;
    for (int p = 0; p < EG_BLOCKS; p++)
        s += partials[(size_t)p * 12288 + gf];
    msg[gf] = s;
}

// ---------------- pooling (x3 sums, counts, degree sums) + head ----------------
__global__ __launch_bounds__(192) void k_pool(const unsigned short* __restrict__ A_,
                                              const int* __restrict__ batch,
                                              const int* __restrict__ indeg,
                                              float* __restrict__ sums, float* __restrict__ cnt,
                                              float* __restrict__ degsum) {
    const int b = blockIdx.x;      // 500 blocks x 200 nodes
    const int f = threadIdx.x;     // 192 features
    const unsigned short* Af = A_ + (size_t)(f >> 4) * (ST0 * 16) + (f & 15);
    int n0 = b * 200;
    int n1 = min(n0 + 200, NN);
    int cur = batch[n0];
    float acc = 0.f;
    int run = 0, dacc = 0;
    for (int n = n0; n < n1; n++) {
        int g = batch[n];
        if (g != cur) {
            atomicAdd(&sums[cur * 192 + f], acc);
            if (f == 0) { atomicAdd(&cnt[cur], (float)run); atomicAdd(&degsum[cur], (float)dacc); }
            acc = 0.f; run = 0; dacc = 0; cur = g;
        }
        acc += b16f(Af[(size_t)n * 16]);
        run++;
        if (f == 0) dacc += indeg[n];
    }
    atomicAdd(&sums[cur * 192 + f], acc);
    if (f == 0) { atomicAdd(&cnt[cur], (float)run); atomicAdd(&degsum[cur], (float)dacc); }
}

__global__ __launch_bounds__(128) void k_head(const float* __restrict__ sums, const float* __restrict__ msg,
                                              const float* __restrict__ cnt, const float* __restrict__ degsum,
                                              const float* __restrict__ W3, const float* __restrict__ b3,
                                              const float* __restrict__ Wfc, const float* __restrict__ bfc,
                                              float* __restrict__ out) {
    __shared__ float py[192];
    __shared__ float tl[128];
    __shared__ float lg[10];
    const int g = blockIdx.x, t = threadIdx.x;
    const float inv = 1.f / fmaxf(cnt[g], 1.f);
    const float ed = 1e-7f * degsum[g];
    for (int k = t; k < 192; k += 128)
        py[k] = (sums[g * 192 + k] + msg[g * 192 + k] + ed) * inv;
    __syncthreads();
    float tf = b3[t];
    for (int k = 0; k < 192; k++) tf += py[k] * W3[k * 128 + t];
    tl[t] = tf;
    __syncthreads();
    if (t < 10) {
        float s = bfc[t];
        for (int f = 0; f < 128; f++) s += tl[f] * Wfc[f * 10 + t];
        lg[t] = s;
    }
    __syncthreads();
    if (t < 10) {
        float m = lg[0];
        for (int k = 1; k < 10; k++) m = fmaxf(m, lg[k]);
        float se = 0.f;
        for (int k = 0; k < 10; k++) se += expf(lg[k] - m);
        out[g * 10 + t] = lg[t] - m - logf(se);
    }
}

// ---------------- workspace layout (bytes) ----------------
constexpr size_t A0_OFF     = 0;                    // 38,400,384 = 12 chunks * CB0
constexpr size_t A1_OFF     = 38400384;             // 38,400,000 = 12 chunks * CB1: slot/perm -> y -> hist/partials
constexpr size_t HIST_REL   = 0;                    // 12,812,288 (64*50048*4)
constexpr size_t PARTS_REL  = 12812288;             // 19,218,432 (391*12288*4) -> ends 32,030,720
constexpr size_t PERM_REL   = 6400000;              // 400,000 (perm; dead after k_pgather, before y writes)
constexpr size_t CSR_OFF    = 76800384;             // 6,400,000
constexpr size_t OFFS_OFF   = 83200384;             // 400,128
constexpr size_t INDEG_OFF  = 83600512;             // 400,000
constexpr size_t PART_OFF   = 84000512;             // 512
constexpr size_t NSTART_OFF = 84001024;             // 256
constexpr size_t WT0_OFF    = 84001280;             // 49,152
constexpr size_t WT1_OFF    = 84050432;             // 73,728
constexpr size_t WT2_OFF    = 84124160;             // 73,728
constexpr size_t SUMS_OFF   = 84197888;             // 49,152
constexpr size_t CNT_OFF    = 84247040;             // 256
constexpr size_t DEGS_OFF   = 84247296;             // 256
constexpr size_t MSG_OFF    = 84247552;             // 49,152 -> 84,296,704
constexpr size_t DBIN_OFF   = 84296704;             // 1,024
constexpr size_t DBOFF_OFF  = 84297728;             // 1,024
constexpr size_t PARR_OFF   = 84298752;             // 1,601,536 (100096 * int4) -> ends 85,900,288

extern "C" void kernel_launch(void* const* d_in, const int* in_sizes, int n_in,
                              void* d_out, int out_size, void* d_ws, size_t ws_size,
                              hipStream_t stream) {
    const float* x   = (const float*)d_in[0];
    const float* W0  = (const float*)d_in[1];
    const float* b0  = (const float*)d_in[2];
    const float* W1  = (const float*)d_in[3];
    const float* b1  = (const float*)d_in[4];
    const float* W2  = (const float*)d_in[5];
    const float* b2  = (const float*)d_in[6];
    const float* W3  = (const float*)d_in[7];
    const float* b3  = (const float*)d_in[8];
    const float* Wfc = (const float*)d_in[9];
    const float* bfc = (const float*)d_in[10];
    const int*   ei  = (const int*)d_in[11];
    const int*   bat = (const int*)d_in[12];
    float* out = (float*)d_out;

    char* ws = (char*)d_ws;
    unsigned short* A0  = (unsigned short*)(ws + A0_OFF);
    unsigned short* A1  = (unsigned short*)(ws + A1_OFF);
    int* slot   = (int*)(ws + A1_OFF);
    int* perm   = (int*)(ws + A1_OFF + PERM_REL);
    unsigned int* hist  = (unsigned int*)(ws + A1_OFF + HIST_REL);
    float* parts        = (float*)(ws + A1_OFF + PARTS_REL);
    int* csr    = (int*)(ws + CSR_OFF);
    int* offs   = (int*)(ws + OFFS_OFF);
    int* indeg  = (int*)(ws + INDEG_OFF);
    int* part   = (int*)(ws + PART_OFF);
    int* nstart = (int*)(ws + NSTART_OFF);
    unsigned short* Wt0 = (unsigned short*)(ws + WT0_OFF);
    unsigned short* Wt1 = (unsigned short*)(ws + WT1_OFF);
    unsigned short* Wt2 = (unsigned short*)(ws + WT2_OFF);
    float* sums   = (float*)(ws + SUMS_OFF);
    float* cnt    = (float*)(ws + CNT_OFF);
    float* degsum = (float*)(ws + DEGS_OFF);
    float* msg    = (float*)(ws + MSG_OFF);
    int* dbin  = (int*)(ws + DBIN_OFF);
    int* dboff = (int*)(ws + DBOFF_OFF);
    int4* parr = (int4*)(ws + PARR_OFF);

    // zero indeg; zero sums+cnt+degsum (contiguous 49,664B); zero degree bins
    hipMemsetAsync(ws + INDEG_OFF, 0, 400000, stream);
    hipMemsetAsync(ws + SUMS_OFF, 0, 49664, stream);
    hipMemsetAsync(ws + DBIN_OFF, 0, 1024, stream);

    // fused preprocessing
    k_prep<<<PREP_GRID, 256, 0, stream>>>(x, ei, bat, W0, W1, W2, A0, indeg, slot,
                                          Wt0, Wt1, Wt2, nstart);

    // offs = exclusive scan(indeg) + degree counting-sort; atomic-free CSR fill
    k_scan1<<<NB_SCAN, 1024, 0, stream>>>(indeg, offs, part, dbin);
    k_scan2<<<1, 256, 0, stream>>>(offs, part, dbin, dboff);
    k_scan3<<<NB_SCAN, 1024, 0, stream>>>(offs, part, indeg, dboff, perm);
    k_fill<<<(NE / 4 + 255) / 256, 256, 0, stream>>>(ei, offs, slot, csr);
    k_pgather<<<391, 256, 0, stream>>>(perm, indeg, offs, parr);

    const int GEMM_GRID = (NN / 32 + 3) / 4;        // 782 blocks
    constexpr int AGG8_GRID  = 8 * 2 * 782;         // 12512
    constexpr int AGG12_GRID = 8 * 3 * 782;         // 18768

    // layers 0..2 (ping-pong A0 <-> A1), chunk-major aggregation
    k_aggc<8><<<AGG8_GRID, 256, 0, stream>>>(A0, A1, parr, csr);
    k_gemm<128, 192><<<GEMM_GRID, 256, 0, stream>>>(A1, Wt0, b0, A0);
    k_aggc<12><<<AGG12_GRID, 256, 0, stream>>>(A0, A1, parr, csr);
    k_gemm<192, 192><<<GEMM_GRID, 256, 0, stream>>>(A1, Wt1, b1, A0);
    k_aggc<12><<<AGG12_GRID, 256, 0, stream>>>(A0, A1, parr, csr);
    k_gemm<192, 192><<<GEMM_GRID, 256, 0, stream>>>(A1, Wt2, b2, A0);   // A0 = x3

    // layer 3 via linearity: pooled(y3) = pooled(x3) + eps*degsum + E @ relu(x3)
    hipMemsetAsync(ws + A1_OFF + HIST_REL, 0, 12812288, stream);        // y2 dead; reuse A1
    k_hist<<<NG * 4, 256, 0, stream>>>(csr, offs, nstart, hist);
    k_egemm<<<EG_BLOCKS, 384, 0, stream>>>(A0, hist, parts);
    k_reduce<<<48, 256, 0, stream>>>(parts, msg);
    k_pool<<<500, 192, 0, stream>>>(A0, bat, indeg, sums, cnt, degsum);
    k_head<<<NG, 128, 0, stream>>>(sums, msg, cnt, degsum, W3, b3, Wfc, bfc, out);
}

// Round 3
// 717.799 us; speedup vs baseline: 2.4281x; 2.4281x over previous
//
#include <hip/hip_runtime.h>
#include <hip/hip_bf16.h>
#include <stdint.h>

// ---------------- problem constants ----------------
constexpr int NN = 100000;     // nodes
constexpr int NE = 1600000;    // edges
constexpr int NG = 64;         // graphs
constexpr int S  = 192;        // row stride (elements) for node-feature buffers
constexpr int NB_SCAN = 98;    // ceil(100000/1024)
constexpr unsigned int ZOFF = (unsigned int)NN * 384u;   // byte offset of the zero row

// prep kernel grid sections (convx | indeg+slot | convw(W0..W2) | nstart)
constexpr int PREP_CONVX_BLK = 12500;   // NN*32/256
constexpr int PREP_INDEG_BLK = 1563;    // ceil(NE/4/256)
constexpr int PREP_CONVW_BLK = 384;     // (24576+36864+36864)/256
constexpr int PREP_GB_BLK    = 391;     // ceil(NN/256)
constexpr int PREP_GRID = PREP_CONVX_BLK + PREP_INDEG_BLK + PREP_CONVW_BLK + PREP_GB_BLK;

// E-GEMM geometry
constexpr int EG_BLOCKS = 391;            // ceil(NN/256), 256 src rows per block
constexpr int HROW = 50048;               // hist row length in u32 (EG_BLOCKS*256/2)

typedef __bf16 bf16x8 __attribute__((ext_vector_type(8)));
typedef float  f32x16 __attribute__((ext_vector_type(16)));
typedef float  f32x2  __attribute__((ext_vector_type(2)));

union U16x4 { uint4 u; bf16x8 b; };

// bf16(packed in uint halves) <-> f32 helpers
__device__ __forceinline__ float bl(unsigned int u) { return __uint_as_float(u << 16); }
__device__ __forceinline__ float bh(unsigned int u) { return __uint_as_float(u & 0xffff0000u); }
__device__ __forceinline__ float b16f(unsigned short u) { return __uint_as_float(((unsigned int)u) << 16); }
__device__ __forceinline__ unsigned int fb(float f) {  // f32 -> bf16 bits, RTNE
    unsigned int u = __float_as_uint(f);
    return (u + 0x7fffu + ((u >> 16) & 1u)) >> 16;
}
// packed bf16 relu: v_pk_max_f16 on raw bits decides on sign/zero only — exact for bf16.
__device__ __forceinline__ unsigned int prelu(unsigned int u) {
    unsigned int r;
    asm("v_pk_max_f16 %0, %1, %2" : "=v"(r) : "v"(u), "v"(0u));
    return r;
}
// two u16 counts -> packed bf16 pair (exact for counts <= 256)
__device__ __forceinline__ unsigned int cnt2bf(unsigned int h) {
    float f0 = (float)(h & 0xffffu);
    float f1 = (float)(h >> 16);
    return (__float_as_uint(f0) >> 16) | (__float_as_uint(f1) & 0xffff0000u);
}

// ---------------- fused preprocessing: convx | indeg+slot | convw | nstart ----------------
__global__ __launch_bounds__(256) void k_prep(const float* __restrict__ x,
                                              const int* __restrict__ ei,
                                              const int* __restrict__ bat,
                                              const float* __restrict__ W0, const float* __restrict__ W1,
                                              const float* __restrict__ W2,
                                              unsigned short* __restrict__ A_,
                                              int* __restrict__ indeg, int* __restrict__ slot,
                                              unsigned short* __restrict__ T0, unsigned short* __restrict__ T1,
                                              unsigned short* __restrict__ T2,
                                              int* __restrict__ nstart) {
    const int b = blockIdx.x;
    if (b < PREP_CONVX_BLK) {
        int id = b * 256 + threadIdx.x;
        if (id < 96) ((unsigned int*)(A_ + (size_t)NN * S))[id] = 0u;   // zero sentinel row
        int row = id >> 5, c4 = id & 31;
        float4 v = ((const float4*)x)[id];
        uint2 a;
        a.x = fb(v.x) | (fb(v.y) << 16);
        a.y = fb(v.z) | (fb(v.w) << 16);
        *(uint2*)(A_ + row * S + c4 * 4) = a;
    } else if (b < PREP_CONVX_BLK + PREP_INDEG_BLK) {
        int e4 = ((b - PREP_CONVX_BLK) * 256 + threadIdx.x) * 4;
        if (e4 < NE) {
            int4 d = *(const int4*)(ei + NE + e4);
            int4 sl;
            sl.x = atomicAdd(&indeg[d.x], 1);
            sl.y = atomicAdd(&indeg[d.y], 1);
            sl.z = atomicAdd(&indeg[d.z], 1);
            sl.w = atomicAdd(&indeg[d.w], 1);
            *(int4*)(slot + e4) = sl;
        }
    } else if (b < PREP_CONVX_BLK + PREP_INDEG_BLK + PREP_CONVW_BLK) {
        int id = (b - PREP_CONVX_BLK - PREP_INDEG_BLK) * 256 + threadIdx.x;
        const float* W; unsigned short* T; int N, base;
        if      (id < 24576) { W = W0; T = T0; N = 192; base = 0;     }
        else if (id < 61440) { W = W1; T = T1; N = 192; base = 24576; }
        else                 { W = W2; T = T2; N = 192; base = 61440; }
        int lid = id - base;
        int ci = lid >> 3, j = lid & 7;
        int kc = ci / N, n = ci % N;
        T[lid] = (unsigned short)fb(W[(kc * 8 + j) * N + n]);
    } else {
        // nstart[g] = first node n with bat[n] >= g (batch sorted); empty graphs ok
        int n = (b - PREP_CONVX_BLK - PREP_INDEG_BLK - PREP_CONVW_BLK) * 256 + threadIdx.x;
        if (n < NN) {
            int b0 = bat[n];
            int bprev = (n == 0) ? -1 : bat[n - 1];
            for (int g = bprev + 1; g <= b0; g++) nstart[g] = n;
            if (n == NN - 1)
                for (int g = b0 + 1; g < NG; g++) nstart[g] = NN;
        }
    }
}

// ---------------- scan of indeg -> offs ----------------
__global__ __launch_bounds__(1024) void k_scan1(const int* __restrict__ indeg, int* __restrict__ offs,
                                                int* __restrict__ partials) {
    __shared__ int s[1024];
    int t = threadIdx.x;
    int gid = blockIdx.x * 1024 + t;
    int v = (gid < NN) ? indeg[gid] : 0;
    s[t] = v;
    __syncthreads();
    for (int d = 1; d < 1024; d <<= 1) {
        int tv = (t >= d) ? s[t - d] : 0;
        __syncthreads();
        s[t] += tv;
        __syncthreads();
    }
    if (gid < NN) offs[gid + 1] = s[t];
    if (t == 1023) partials[blockIdx.x] = s[1023];
}

__global__ __launch_bounds__(128) void k_scan2(int* __restrict__ offs, int* __restrict__ partials) {
    __shared__ int s[128];
    int t = threadIdx.x;
    int v = (t < NB_SCAN) ? partials[t] : 0;
    s[t] = v;
    __syncthreads();
    for (int d = 1; d < 128; d <<= 1) {
        int tv = (t >= d) ? s[t - d] : 0;
        __syncthreads();
        s[t] += tv;
        __syncthreads();
    }
    if (t < NB_SCAN) partials[t] = s[t] - v;
    if (t == 0) offs[0] = 0;
}

__global__ __launch_bounds__(1024) void k_scan3(int* __restrict__ offs, const int* __restrict__ partials) {
    int gid = blockIdx.x * 1024 + threadIdx.x;
    if (gid < NN) offs[gid + 1] += partials[blockIdx.x];
}

// ---------------- atomic-free CSR fill ----------------
__global__ __launch_bounds__(256) void k_fill(const int* __restrict__ ei, const int* __restrict__ offs,
                                              const int* __restrict__ slot, int* __restrict__ csr) {
    int e4 = (blockIdx.x * 256 + threadIdx.x) * 4;
    if (e4 >= NE) return;
    int4 sv = *(const int4*)(ei + e4);
    int4 dv = *(const int4*)(ei + NE + e4);
    int4 sl = *(const int4*)(slot + e4);
    csr[offs[dv.x] + sl.x] = sv.x;
    csr[offs[dv.y] + sl.y] = sv.y;
    csr[offs[dv.z] + sl.z] = sv.z;
    csr[offs[dv.w] + sl.w] = sv.w;
}

// ---------------- aggregation (layers 0..2) ----------------
__global__ __launch_bounds__(256, 8) void k_agg192(const unsigned short* __restrict__ Ain,
                                                   unsigned short* __restrict__ Yout,
                                                   const int* __restrict__ offs,
                                                   const int* __restrict__ indeg,
                                                   const int* __restrict__ csr) {
    const int w = threadIdx.x >> 6, lane = threadIdx.x & 63;
    const int i = __builtin_amdgcn_readfirstlane(blockIdx.x * 4 + w);
    const bool act = lane < 48;
    const int deg   = __builtin_amdgcn_readfirstlane(indeg[i]);
    const int start = __builtin_amdgcn_readfirstlane(offs[i]);
    const int fo = (act ? lane : 47) * 8;
    const char* Ab = (const char*)Ain;

    f32x2 A01, A23;
    {
        uint2 p = *(const uint2*)(Ab + (size_t)i * 384 + fo);
        const float ed = 1e-7f * (float)deg;
        A01 = (f32x2){bl(p.x) + ed, bh(p.x) + ed};
        A23 = (f32x2){bl(p.y) + ed, bh(p.y) + ed};
    }

    const int* ecsr = csr + start;
    for (int e = 0; e < deg; e += 16) {
        unsigned int off[16];
#pragma unroll
        for (int k = 0; k < 16; k++) {
            int v = ecsr[e + k];
            off[k] = (e + k < deg) ? (unsigned int)v * 384u : ZOFF;
        }
        uint2 p[16];
#pragma unroll
        for (int k = 0; k < 16; k++)
            p[k] = *(const uint2*)(Ab + (size_t)off[k] + fo);
#pragma unroll
        for (int k = 0; k < 16; k++) {
            unsigned int rx = prelu(p[k].x), ry = prelu(p[k].y);
            A01 += (f32x2){bl(rx), bh(rx)};
            A23 += (f32x2){bl(ry), bh(ry)};
        }
    }
    if (act) {
        uint2 o;
        o.x = fb(A01.x) | (fb(A01.y) << 16);
        o.y = fb(A23.x) | (fb(A23.y) << 16);
        *(uint2*)(Yout + (size_t)i * S + lane * 4) = o;
    }
}

__global__ __launch_bounds__(256, 8) void k_agg128(const unsigned short* __restrict__ Ain,
                                                   unsigned short* __restrict__ Yout,
                                                   const int* __restrict__ offs,
                                                   const int* __restrict__ indeg,
                                                   const int* __restrict__ csr) {
    const int w = threadIdx.x >> 6, lane = threadIdx.x & 63;
    const int i = __builtin_amdgcn_readfirstlane(blockIdx.x * 4 + w);
    const int deg   = __builtin_amdgcn_readfirstlane(indeg[i]);
    const int start = __builtin_amdgcn_readfirstlane(offs[i]);
    const int fo = lane * 4;
    const char* Ab = (const char*)Ain;

    f32x2 A01;
    {
        unsigned int p = *(const unsigned int*)(Ab + (size_t)i * 384 + fo);
        const float ed = 1e-7f * (float)deg;
        A01 = (f32x2){bl(p) + ed, bh(p) + ed};
    }

    const int* ecsr = csr + start;
    for (int e = 0; e < deg; e += 16) {
        unsigned int off[16];
#pragma unroll
        for (int k = 0; k < 16; k++) {
            int v = ecsr[e + k];
            off[k] = (e + k < deg) ? (unsigned int)v * 384u : ZOFF;
        }
        unsigned int q[16];
#pragma unroll
        for (int k = 0; k < 16; k++)
            q[k] = *(const unsigned int*)(Ab + (size_t)off[k] + fo);
#pragma unroll
        for (int k = 0; k < 16; k++) {
            unsigned int r = prelu(q[k]);
            A01 += (f32x2){bl(r), bh(r)};
        }
    }
    *(unsigned int*)(Yout + (size_t)i * S + lane * 2) =
        fb(A01.x) | (fb(A01.y) << 16);
}

// ---------------- GEMM: h = y @ W + b (layers 0..2) ----------------
template <int K, int N>
__global__ __launch_bounds__(256) void k_gemm(const unsigned short* __restrict__ Yin,
                                              const unsigned short* __restrict__ WtC,
                                              const float* __restrict__ bias,
                                              unsigned short* __restrict__ Aout) {
    static_assert(K % 16 == 0 && N % 32 == 0, "");
    const int w = threadIdx.x >> 6, lane = threadIdx.x & 63;
    const int rt = blockIdx.x * 4 + w;
    if (rt >= (NN / 32)) return;
    const int hl = lane >> 5, lr = lane & 31;
    const int row0 = rt * 32;
    f32x16 acc[N / 32];
#pragma unroll
    for (int c = 0; c < N / 32; c++)
#pragma unroll
        for (int r = 0; r < 16; r++) acc[c][r] = 0.f;

    const unsigned short* ap = Yin + (row0 + lr) * S + hl * 8;
    const uint4* b4 = (const uint4*)WtC;
#pragma unroll
    for (int ks = 0; ks < K / 16; ks++) {
        U16x4 a;
        a.u = *(const uint4*)(ap + ks * 16);
#pragma unroll
        for (int c = 0; c < N / 32; c++) {
            U16x4 b;
            b.u = b4[(ks * 2 + hl) * N + c * 32 + lr];
            acc[c] = __builtin_amdgcn_mfma_f32_32x32x16_bf16(a.b, b.b, acc[c], 0, 0, 0);
        }
    }
#pragma unroll
    for (int c = 0; c < N / 32; c++) {
        const int col = c * 32 + lr;
        const float bc = bias[col];
#pragma unroll
        for (int r = 0; r < 16; r++) {
            const int row = row0 + (r & 3) + 8 * (r >> 2) + 4 * hl;
            Aout[row * S + col] = (unsigned short)fb(acc[c][r] + bc);
        }
    }
}

// ---------------- layer-3 replacement: E-matrix path ----------------
// hist[g][j] u16-pair packed: count of edges j -> graph g. One block per graph:
// zero own 200KB row, sync, then walk the graph's csr range (graph-contiguous CSR)
// with coalesced reads; atomics confined to the one row. Fuses the old 12.8MB memset.
__global__ __launch_bounds__(1024) void k_hist(const int* __restrict__ csr, const int* __restrict__ offs,
                                               const int* __restrict__ nstart,
                                               unsigned int* __restrict__ hist) {
    const int g = blockIdx.x;
    unsigned int* hrow = hist + (size_t)g * HROW;
    for (int i = threadIdx.x; i < HROW; i += 1024) hrow[i] = 0u;
    __syncthreads();
    const int s0 = offs[nstart[g]];
    const int s1 = (g == NG - 1) ? NE : offs[nstart[g + 1]];
    for (int p = s0 + threadIdx.x; p < s1; p += 1024) {
        int src = csr[p];
        atomicAdd(&hrow[src >> 1], 1u << (16 * (src & 1)));
    }
}

// msg-partials: P[g][f] += count(j->g) * relu(x3[j][f]) over block's 256-row K slice.
// 384 threads = 6 waves; wave wv owns feat tile wv (32 feats), both 32-g tiles.
// E A-fragment built on the fly from hist (u16 counts -> bf16, exact).
__global__ __launch_bounds__(384) void k_egemm(const unsigned short* __restrict__ A0,
                                               const unsigned int* __restrict__ hist,
                                               float* __restrict__ partials) {
    const int wv = threadIdx.x >> 6, lane = threadIdx.x & 63;
    const int b = blockIdx.x;
    const int j0 = b * 256;
    const int hl = lane >> 5, lr = lane & 31;
    const int feat = wv * 32 + lr;
    f32x16 acc[2];
#pragma unroll
    for (int m = 0; m < 2; m++)
#pragma unroll
        for (int r = 0; r < 16; r++) acc[m][r] = 0.f;

    for (int kk = 0; kk < 16; kk++) {
        // A-operand: counts for g = m*32+lr, j = j0+kk*16+hl*8 .. +8
        const int jh = (j0 >> 1) + kk * 8 + hl * 4;
        U16x4 af[2];
#pragma unroll
        for (int m = 0; m < 2; m++) {
            uint4 h = *(const uint4*)(hist + (size_t)(m * 32 + lr) * HROW + jh);
            af[m].u = (uint4){cnt2bf(h.x), cnt2bf(h.y), cnt2bf(h.z), cnt2bf(h.w)};
        }
        // B-operand: relu(x3[j][feat]) for the same 8 j
        U16x4 bf;
#pragma unroll
        for (int tp = 0; tp < 4; tp++) {
            int je = j0 + kk * 16 + hl * 8 + tp * 2;
            int ja = min(je, NN), jb = min(je + 1, NN);   // sentinel zero row
            unsigned int u0 = A0[(size_t)ja * S + feat];
            unsigned int u1 = A0[(size_t)jb * S + feat];
            ((unsigned int*)&bf.u)[tp] = prelu(u0 | (u1 << 16));
        }
#pragma unroll
        for (int m = 0; m < 2; m++)
            acc[m] = __builtin_amdgcn_mfma_f32_32x32x16_bf16(af[m].b, bf.b, acc[m], 0, 0, 0);
    }
    float* pb = partials + (size_t)b * 12288;
#pragma unroll
    for (int m = 0; m < 2; m++)
#pragma unroll
        for (int r = 0; r < 16; r++) {
            const int g = m * 32 + (r & 3) + 8 * (r >> 2) + 4 * hl;
            pb[g * 192 + feat] = acc[m][r];
        }
}

// reduce f32 partials -> msg f32 [64][192]
__global__ __launch_bounds__(256) void k_reduce(const float* __restrict__ partials,
                                                float* __restrict__ msg) {
    int gf = blockIdx.x * 256 + threadIdx.x;     // 12288 total
    if (gf >= 12288) return;
    float s = 0.f;
    for (int p = 0; p < EG_BLOCKS; p++)
        s += partials[(size_t)p * 12288 + gf];
    msg[gf] = s;
}

// ---------------- pooling (x3 sums, counts, degree sums) + head ----------------
__global__ __launch_bounds__(192) void k_pool(const unsigned short* __restrict__ A_,
                                              const int* __restrict__ batch,
                                              const int* __restrict__ indeg,
                                              float* __restrict__ sums, float* __restrict__ cnt,
                                              float* __restrict__ degsum) {
    const int b = blockIdx.x;      // 500 blocks x 200 nodes
    const int f = threadIdx.x;     // 192 features
    int n0 = b * 200;
    int n1 = min(n0 + 200, NN);
    int cur = batch[n0];
    float acc = 0.f;
    int run = 0, dacc = 0;
    for (int n = n0; n < n1; n++) {
        int g = batch[n];
        if (g != cur) {
            atomicAdd(&sums[cur * 192 + f], acc);
            if (f == 0) { atomicAdd(&cnt[cur], (float)run); atomicAdd(&degsum[cur], (float)dacc); }
            acc = 0.f; run = 0; dacc = 0; cur = g;
        }
        acc += b16f(A_[(size_t)n * S + f]);
        run++;
        if (f == 0) dacc += indeg[n];
    }
    atomicAdd(&sums[cur * 192 + f], acc);
    if (f == 0) { atomicAdd(&cnt[cur], (float)run); atomicAdd(&degsum[cur], (float)dacc); }
}

__global__ __launch_bounds__(128) void k_head(const float* __restrict__ sums, const float* __restrict__ msg,
                                              const float* __restrict__ cnt, const float* __restrict__ degsum,
                                              const float* __restrict__ W3, const float* __restrict__ b3,
                                              const float* __restrict__ Wfc, const float* __restrict__ bfc,
                                              float* __restrict__ out) {
    __shared__ float py[192];
    __shared__ float tl[128];
    __shared__ float lg[10];
    const int g = blockIdx.x, t = threadIdx.x;
    const float inv = 1.f / fmaxf(cnt[g], 1.f);
    const float ed = 1e-7f * degsum[g];
    for (int k = t; k < 192; k += 128)
        py[k] = (sums[g * 192 + k] + msg[g * 192 + k] + ed) * inv;
    __syncthreads();
    float tf = b3[t];
    for (int k = 0; k < 192; k++) tf += py[k] * W3[k * 128 + t];
    tl[t] = tf;
    __syncthreads();
    if (t < 10) {
        float s = bfc[t];
        for (int f = 0; f < 128; f++) s += tl[f] * Wfc[f * 10 + t];
        lg[t] = s;
    }
    __syncthreads();
    if (t < 10) {
        float m = lg[0];
        for (int k = 1; k < 10; k++) m = fmaxf(m, lg[k]);
        float se = 0.f;
        for (int k = 0; k < 10; k++) se += expf(lg[k] - m);
        out[g * 10 + t] = lg[t] - m - logf(se);
    }
}

// ---------------- workspace layout (bytes) ----------------
// INDEG..DEGS contiguous so one memset clears indeg+sums+cnt+degsum (449,664 B).
constexpr size_t A0_OFF     = 0;                    // 38,400,384 (incl zero row NN)
constexpr size_t A1_OFF     = 38400384;             // 38,400,000: slot -> y -> hist/partials
constexpr size_t HIST_REL   = 0;                    // 12,812,288 (64*50048*4)
constexpr size_t PARTS_REL  = 12812288;             // 19,218,432 (391*12288*4) -> ends 32,030,720
constexpr size_t CSR_OFF    = 76800384;             // 6,400,000
constexpr size_t OFFS_OFF   = 83200384;             // 400,128
constexpr size_t INDEG_OFF  = 83600512;             // 400,000
constexpr size_t SUMS_OFF   = 84000512;             // 49,152
constexpr size_t CNT_OFF    = 84049664;             // 256
constexpr size_t DEGS_OFF   = 84049920;             // 256 -> zero-region ends 84,050,176
constexpr size_t PART_OFF   = 84050176;             // 512
constexpr size_t NSTART_OFF = 84050688;             // 256
constexpr size_t WT0_OFF    = 84050944;             // 49,152
constexpr size_t WT1_OFF    = 84100096;             // 73,728
constexpr size_t WT2_OFF    = 84173824;             // 73,728
constexpr size_t MSG_OFF    = 84247552;             // 49,152 -> ends 84,296,704

extern "C" void kernel_launch(void* const* d_in, const int* in_sizes, int n_in,
                              void* d_out, int out_size, void* d_ws, size_t ws_size,
                              hipStream_t stream) {
    const float* x   = (const float*)d_in[0];
    const float* W0  = (const float*)d_in[1];
    const float* b0  = (const float*)d_in[2];
    const float* W1  = (const float*)d_in[3];
    const float* b1  = (const float*)d_in[4];
    const float* W2  = (const float*)d_in[5];
    const float* b2  = (const float*)d_in[6];
    const float* W3  = (const float*)d_in[7];
    const float* b3  = (const float*)d_in[8];
    const float* Wfc = (const float*)d_in[9];
    const float* bfc = (const float*)d_in[10];
    const int*   ei  = (const int*)d_in[11];
    const int*   bat = (const int*)d_in[12];
    float* out = (float*)d_out;

    char* ws = (char*)d_ws;
    unsigned short* A0  = (unsigned short*)(ws + A0_OFF);
    unsigned short* A1  = (unsigned short*)(ws + A1_OFF);
    int* slot   = (int*)(ws + A1_OFF);
    unsigned int* hist  = (unsigned int*)(ws + A1_OFF + HIST_REL);
    float* parts        = (float*)(ws + A1_OFF + PARTS_REL);
    int* csr    = (int*)(ws + CSR_OFF);
    int* offs   = (int*)(ws + OFFS_OFF);
    int* indeg  = (int*)(ws + INDEG_OFF);
    int* part   = (int*)(ws + PART_OFF);
    int* nstart = (int*)(ws + NSTART_OFF);
    unsigned short* Wt0 = (unsigned short*)(ws + WT0_OFF);
    unsigned short* Wt1 = (unsigned short*)(ws + WT1_OFF);
    unsigned short* Wt2 = (unsigned short*)(ws + WT2_OFF);
    float* sums   = (float*)(ws + SUMS_OFF);
    float* cnt    = (float*)(ws + CNT_OFF);
    float* degsum = (float*)(ws + DEGS_OFF);
    float* msg    = (float*)(ws + MSG_OFF);

    // one memset: indeg + sums + cnt + degsum (contiguous 449,664 B)
    hipMemsetAsync(ws + INDEG_OFF, 0, 449664, stream);

    // fused preprocessing
    k_prep<<<PREP_GRID, 256, 0, stream>>>(x, ei, bat, W0, W1, W2, A0, indeg, slot,
                                          Wt0, Wt1, Wt2, nstart);

    // offs = exclusive scan(indeg); atomic-free CSR fill
    k_scan1<<<NB_SCAN, 1024, 0, stream>>>(indeg, offs, part);
    k_scan2<<<1, 128, 0, stream>>>(offs, part);
    k_scan3<<<NB_SCAN, 1024, 0, stream>>>(offs, part);
    k_fill<<<(NE / 4 + 255) / 256, 256, 0, stream>>>(ei, offs, slot, csr);

    const int AGG_GRID  = NN / 4;                   // 25000 blocks
    const int GEMM_GRID = (NN / 32 + 3) / 4;        // 782 blocks

    // layers 0..2 (ping-pong A0 <-> A1)
    k_agg128<<<AGG_GRID, 256, 0, stream>>>(A0, A1, offs, indeg, csr);
    k_gemm<128, 192><<<GEMM_GRID, 256, 0, stream>>>(A1, Wt0, b0, A0);
    k_agg192<<<AGG_GRID, 256, 0, stream>>>(A0, A1, offs, indeg, csr);
    k_gemm<192, 192><<<GEMM_GRID, 256, 0, stream>>>(A1, Wt1, b1, A0);
    k_agg192<<<AGG_GRID, 256, 0, stream>>>(A0, A1, offs, indeg, csr);
    k_gemm<192, 192><<<GEMM_GRID, 256, 0, stream>>>(A1, Wt2, b2, A0);   // A0 = x3

    // layer 3 via linearity: pooled(y3) = pooled(x3) + eps*degsum + E @ relu(x3)
    // (k_hist zeroes its own hist row; y2 dead so the A1 alias is safe)
    k_hist<<<NG, 1024, 0, stream>>>(csr, offs, nstart, hist);
    k_egemm<<<EG_BLOCKS, 384, 0, stream>>>(A0, hist, parts);
    k_reduce<<<48, 256, 0, stream>>>(parts, msg);
    k_pool<<<500, 192, 0, stream>>>(A0, bat, indeg, sums, cnt, degsum);
    k_head<<<NG, 128, 0, stream>>>(sums, msg, cnt, degsum, W3, b3, Wfc, bfc, out);
}